// Round 2
// baseline (233.724 us; speedup 1.0000x reference)
//
#include <hip/hip_runtime.h>

typedef unsigned short ushort_t;
typedef unsigned int uint32;
typedef __attribute__((ext_vector_type(8))) short s16x8;   // 8 bf16 in 4 VGPRs
typedef __attribute__((ext_vector_type(4))) float f32x4;   // MFMA accumulator

#define BB   16
#define CC   256
#define NPX  4096          // 64*64 pixels
#define EE   4
#define HID  128
#define RHH  128
#define PW   66            // padded image width
#define PPX  (66*66)       // padded pixels per image

__device__ __forceinline__ ushort_t f2bf(float f) {
  uint32 x = __float_as_uint(f);
  x += 0x7fffu + ((x >> 16) & 1u);           // round-to-nearest-even
  return (ushort_t)(x >> 16);
}
// async global->LDS, 16B per lane; lds ptr wave-uniform (HW adds lane*16)
__device__ __forceinline__ void g2l16(const void* g, void* l) {
  __builtin_amdgcn_global_load_lds((const __attribute__((address_space(1))) uint32*)g,
                                   (__attribute__((address_space(3))) uint32*)l, 16, 0, 0);
}

// ---------- x[b][c][px] fp32 -> xT[b][px][c] bf16 (LDS transpose) ----------
__global__ __launch_bounds__(256)
void k_xpose(const float* __restrict__ x, ushort_t* __restrict__ xT) {
  int px0 = blockIdx.x * 64, c0 = blockIdx.y * 64, b = blockIdx.z;
  int t = threadIdx.x;
  __shared__ float T[64][65];
  const float* xg = x + (size_t)b * CC * NPX;
  int cr = t >> 4, p4 = (t & 15) * 4;
#pragma unroll
  for (int i = 0; i < 4; ++i) {
    float4 v = *(const float4*)(xg + (size_t)(c0 + cr + i * 16) * NPX + px0 + p4);
    T[cr + i * 16][p4 + 0] = v.x; T[cr + i * 16][p4 + 1] = v.y;
    T[cr + i * 16][p4 + 2] = v.z; T[cr + i * 16][p4 + 3] = v.w;
  }
  __syncthreads();
  int px = t >> 2, cg = (t & 3) * 16;
  uint32 o[8];
#pragma unroll
  for (int u = 0; u < 8; ++u) {
    uint32 lo = f2bf(T[cg + 2 * u][px]);
    uint32 hi = f2bf(T[cg + 2 * u + 1][px]);
    o[u] = lo | (hi << 16);
  }
  ushort_t* dst = xT + ((size_t)b * NPX + px0 + px) * CC + c0 + cg;
  *(uint4*)dst = make_uint4(o[0], o[1], o[2], o[3]);
  *(uint4*)(dst + 8) = make_uint4(o[4], o[5], o[6], o[7]);
}

// ---------- W1/W3 fp32 -> bf16 (layout preserved) ----------
__global__ __launch_bounds__(256)
void k_wcvt(const float* __restrict__ W1f, const float* __restrict__ W3f,
            ushort_t* __restrict__ W1b, ushort_t* __restrict__ W3b) {
  int i4 = (blockIdx.x * 256 + threadIdx.x) * 4;
  const float* src; ushort_t* dst; int off;
  if (i4 < EE * HID * CC) { src = W1f; dst = W1b; off = i4; }
  else { src = W3f; dst = W3b; off = i4 - EE * HID * CC; }
  float4 v = *(const float4*)(src + off);
  ushort4 o;
  o.x = f2bf(v.x); o.y = f2bf(v.y); o.z = f2bf(v.z); o.w = f2bf(v.w);
  *(ushort4*)(dst + off) = o;
}

// ---------- W2 [E][O][I][3][3] fp32 -> W2r [E][tap][O][I] bf16 ----------
__global__ __launch_bounds__(256)
void k_repack(const float* __restrict__ W2f, ushort_t* __restrict__ W2r) {
  int i = blockIdx.x * 256 + threadIdx.x;   // i = ((e*9+tap)*128+g)*128+h
  int h = i & 127;
  int g = (i >> 7) & 127;
  int et = i >> 14;
  int tap = et % 9;
  int e = et / 9;
  W2r[i] = f2bf(W2f[((((size_t)e * 128 + g) * 128 + h) * 3 + tap / 3) * 3 + tap % 3]);
}

// ---------- pooling: pooled[b][c] = mean over 4096 px (fp32) ----------
__global__ __launch_bounds__(256)
void k_pool(const float* __restrict__ x, float* __restrict__ pooled) {
  int b = blockIdx.y;
  int c0 = blockIdx.x * 16;
  int wave = threadIdx.x >> 6, lane = threadIdx.x & 63;
  for (int i = 0; i < 4; ++i) {
    int c = c0 + wave * 4 + i;
    const float* p = x + ((size_t)b * CC + c) * NPX;
    float s = 0.f;
#pragma unroll
    for (int j = 0; j < 16; ++j) {
      float4 v = *(const float4*)(p + (j * 64 + lane) * 4);
      s += v.x + v.y + v.z + v.w;
    }
#pragma unroll
    for (int off = 32; off > 0; off >>= 1) s += __shfl_down(s, off, 64);
    if (lane == 0) pooled[b * CC + c] = s * (1.0f / NPX);
  }
}

// ---------- router: MLP + softmax + top-1 (fp32) ----------
__global__ __launch_bounds__(128)
void k_router(const float* __restrict__ pooled, const float* __restrict__ Wr1,
              const float* __restrict__ br1, const float* __restrict__ Wr2,
              const float* __restrict__ br2, int* __restrict__ eidx,
              float* __restrict__ gatew) {
  int b = blockIdx.x, t = threadIdx.x;
  __shared__ float hb[RHH];
  __shared__ float lg[EE];
  float a = br1[t];
  const float* pb = pooled + b * CC;
  const float* wr = Wr1 + t * CC;
  for (int c = 0; c < CC; ++c) a += pb[c] * wr[c];
  hb[t] = a > 0.f ? a : 0.f;
  __syncthreads();
  if (t < EE) {
    float s = br2[t];
    const float* w2 = Wr2 + t * RHH;
    for (int r = 0; r < RHH; ++r) s += hb[r] * w2[r];
    lg[t] = s;
  }
  __syncthreads();
  if (t == 0) {
    float m = lg[0]; int mi = 0;
    for (int e = 1; e < EE; ++e) if (lg[e] > m) { m = lg[e]; mi = e; }  // first-max = lax.top_k tie rule
    float den = 0.f;
    for (int e = 0; e < EE; ++e) den += expf(lg[e] - m);
    float v = 1.0f / den;                 // softmax value at argmax
    eidx[b] = mi;
    gatew[b] = v / (v + 1e-9f);           // top-1 renormalized weight
  }
}

// ---------- conv1: 1x1 C->HID, relu -> zero-padded pixel-major y1 ----------
// GEMM: M=128 px, N=128 hid, K=256 c. A=xT (px-major), B=W1b (n-major), both k-contiguous.
__global__ __launch_bounds__(256)
void k_conv1(const ushort_t* __restrict__ xT, const ushort_t* __restrict__ W1b,
             const int* __restrict__ eidx, ushort_t* __restrict__ y1Tp) {
  int mt = blockIdx.x, b = blockIdx.y;
  int e = eidx[b];
  int t = threadIdx.x, wave = t >> 6, lane = t & 63;
  int wm = (wave & 1) * 64, wn = (wave >> 1) * 64;
  __shared__ ushort_t At[128 * 32];
  __shared__ ushort_t Bt[128 * 32];
  f32x4 acc[4][4] = {};
  const ushort_t* ab = xT + ((size_t)b * NPX + mt * 128) * CC;
  const ushort_t* w1 = W1b + (size_t)e * HID * CC;

  for (int ks = 0; ks < 8; ++ks) {
    int k0 = ks * 32;
    __syncthreads();
#pragma unroll
    for (int s = 0; s < 2; ++s) {
      int q = wave * 2 + s;
      int rowi = q * 16 + (lane >> 2);
      int kc = (lane & 3) * 8;
      g2l16(ab + (size_t)rowi * CC + k0 + kc, &At[q * 512]);
      g2l16(w1 + (size_t)rowi * CC + k0 + kc, &Bt[q * 512]);
    }
    __syncthreads();
    s16x8 af[4], bfr[4];
#pragma unroll
    for (int i = 0; i < 4; ++i)
      af[i] = *(const s16x8*)&At[(wm + i * 16 + (lane & 15)) * 32 + (lane >> 4) * 8];
#pragma unroll
    for (int j = 0; j < 4; ++j)
      bfr[j] = *(const s16x8*)&Bt[(wn + j * 16 + (lane & 15)) * 32 + (lane >> 4) * 8];
#pragma unroll
    for (int i = 0; i < 4; ++i)
#pragma unroll
      for (int j = 0; j < 4; ++j)
        acc[i][j] = __builtin_amdgcn_mfma_f32_16x16x32_bf16(af[i], bfr[j], acc[i][j], 0, 0, 0);
  }
  ushort_t* yb = y1Tp + (size_t)b * PPX * HID;
#pragma unroll
  for (int i = 0; i < 4; ++i) {
#pragma unroll
    for (int r = 0; r < 4; ++r) {
      int m = wm + i * 16 + (lane >> 4) * 4 + r;
      int prow = mt * 2 + (m >> 6) + 1;
      int pcol = (m & 63) + 1;
      ushort_t* row = yb + ((size_t)prow * PW + pcol) * HID + wn + (lane & 15);
#pragma unroll
      for (int j = 0; j < 4; ++j) {
        float v = acc[i][j][r];
        row[j * 16] = f2bf(v > 0.f ? v : 0.f);
      }
    }
  }
}

// ---------- conv2: 3x3 HID->HID as 9 shifted GEMM taps ----------
__global__ __launch_bounds__(256)
void k_conv2(const ushort_t* __restrict__ y1Tp, const ushort_t* __restrict__ W2r,
             const int* __restrict__ eidx, ushort_t* __restrict__ y2T) {
  int mt = blockIdx.x, b = blockIdx.y;
  int e = eidx[b];
  int t = threadIdx.x, wave = t >> 6, lane = t & 63;
  int wm = (wave & 1) * 64, wn = (wave >> 1) * 64;
  __shared__ ushort_t At[128 * 32];
  __shared__ ushort_t Bt[128 * 32];
  f32x4 acc[4][4] = {};
  const ushort_t* yb = y1Tp + (size_t)b * PPX * HID;
  const ushort_t* w2e = W2r + (size_t)e * 9 * HID * HID;

  for (int tap = 0; tap < 9; ++tap) {
    int dy = tap / 3 - 1, dx = tap % 3 - 1;
    const ushort_t* w2t = w2e + tap * HID * HID;
    for (int ks = 0; ks < 4; ++ks) {
      int k0 = ks * 32;
      __syncthreads();
#pragma unroll
      for (int s = 0; s < 2; ++s) {
        int q = wave * 2 + s;
        int rowi = q * 16 + (lane >> 2);
        int kc = (lane & 3) * 8;
        int prow = mt * 2 + (rowi >> 6) + 1 + dy;   // shifted padded pixel
        int pcol = (rowi & 63) + 1 + dx;
        g2l16(yb + ((size_t)prow * PW + pcol) * HID + k0 + kc, &At[q * 512]);
        g2l16(w2t + rowi * HID + k0 + kc, &Bt[q * 512]);
      }
      __syncthreads();
      s16x8 af[4], bfr[4];
#pragma unroll
      for (int i = 0; i < 4; ++i)
        af[i] = *(const s16x8*)&At[(wm + i * 16 + (lane & 15)) * 32 + (lane >> 4) * 8];
#pragma unroll
      for (int j = 0; j < 4; ++j)
        bfr[j] = *(const s16x8*)&Bt[(wn + j * 16 + (lane & 15)) * 32 + (lane >> 4) * 8];
#pragma unroll
      for (int i = 0; i < 4; ++i)
#pragma unroll
        for (int j = 0; j < 4; ++j)
          acc[i][j] = __builtin_amdgcn_mfma_f32_16x16x32_bf16(af[i], bfr[j], acc[i][j], 0, 0, 0);
    }
  }
  ushort_t* ob = y2T + ((size_t)b * NPX + (size_t)mt * 128) * HID;
#pragma unroll
  for (int i = 0; i < 4; ++i) {
#pragma unroll
    for (int r = 0; r < 4; ++r) {
      int m = wm + i * 16 + (lane >> 4) * 4 + r;
      ushort_t* row = ob + (size_t)m * HID + wn + (lane & 15);
#pragma unroll
      for (int j = 0; j < 4; ++j) {
        float v = acc[i][j][r];
        row[j * 16] = f2bf(v > 0.f ? v : 0.f);
      }
    }
  }
}

// ---------- conv3: 1x1 HID->C, gate-weighted + fp32 residual, fp32 out ----------
__global__ __launch_bounds__(256)
void k_conv3(const ushort_t* __restrict__ y2T, const ushort_t* __restrict__ W3b,
             const float* __restrict__ x, const int* __restrict__ eidx,
             const float* __restrict__ gatew, float* __restrict__ out) {
  int mt = blockIdx.x, nt = blockIdx.y, b = blockIdx.z;
  int e = eidx[b];
  float gw = gatew[b];
  int t = threadIdx.x, wave = t >> 6, lane = t & 63;
  int wm = (wave & 1) * 64, wn = (wave >> 1) * 64;
  __shared__ ushort_t At[128 * 32];
  __shared__ ushort_t Bt[128 * 32];
  f32x4 acc[4][4] = {};
  const ushort_t* yb = y2T + ((size_t)b * NPX + (size_t)mt * 128) * HID;
  const ushort_t* w3 = W3b + ((size_t)e * CC + nt * 128) * HID;

  for (int ks = 0; ks < 4; ++ks) {
    int k0 = ks * 32;
    __syncthreads();
#pragma unroll
    for (int s = 0; s < 2; ++s) {
      int q = wave * 2 + s;
      int rowi = q * 16 + (lane >> 2);
      int kc = (lane & 3) * 8;
      g2l16(yb + (size_t)rowi * HID + k0 + kc, &At[q * 512]);
      g2l16(w3 + (size_t)rowi * HID + k0 + kc, &Bt[q * 512]);
    }
    __syncthreads();
    s16x8 af[4], bfr[4];
#pragma unroll
    for (int i = 0; i < 4; ++i)
      af[i] = *(const s16x8*)&At[(wm + i * 16 + (lane & 15)) * 32 + (lane >> 4) * 8];
#pragma unroll
    for (int j = 0; j < 4; ++j)
      bfr[j] = *(const s16x8*)&Bt[(wn + j * 16 + (lane & 15)) * 32 + (lane >> 4) * 8];
#pragma unroll
    for (int i = 0; i < 4; ++i)
#pragma unroll
      for (int j = 0; j < 4; ++j)
        acc[i][j] = __builtin_amdgcn_mfma_f32_16x16x32_bf16(af[i], bfr[j], acc[i][j], 0, 0, 0);
  }
  // out[b][c][px] = gw*acc + x ; lane's 4 regs are 4 consecutive px -> float4 I/O
#pragma unroll
  for (int i = 0; i < 4; ++i) {
    int px = mt * 128 + wm + i * 16 + (lane >> 4) * 4;
#pragma unroll
    for (int j = 0; j < 4; ++j) {
      int c = nt * 128 + wn + j * 16 + (lane & 15);
      size_t base = ((size_t)b * CC + c) * NPX + px;
      float4 xa = *(const float4*)(x + base);
      float4 o;
      o.x = gw * acc[i][j][0] + xa.x;
      o.y = gw * acc[i][j][1] + xa.y;
      o.z = gw * acc[i][j][2] + xa.z;
      o.w = gw * acc[i][j][3] + xa.w;
      *(float4*)(out + base) = o;
    }
  }
}

extern "C" void kernel_launch(void* const* d_in, const int* in_sizes, int n_in,
                              void* d_out, int out_size, void* d_ws, size_t ws_size,
                              hipStream_t stream) {
  const float* x   = (const float*)d_in[0];
  const float* Wr1 = (const float*)d_in[1];
  const float* br1 = (const float*)d_in[2];
  const float* Wr2 = (const float*)d_in[3];
  const float* br2 = (const float*)d_in[4];
  const float* W1  = (const float*)d_in[5];
  const float* W2  = (const float*)d_in[6];
  const float* W3  = (const float*)d_in[7];
  float* out = (float*)d_out;

  char* ws = (char*)d_ws;
  int*      eidx   = (int*)ws;                        // 64 B
  float*    gatew  = (float*)(ws + 64);               // 64 B
  float*    pooled = (float*)(ws + 256);              // 16 KB -> 16640
  ushort_t* W1b    = (ushort_t*)(ws + 16640);         // 256 KB -> 278784
  ushort_t* W3b    = (ushort_t*)(ws + 278784);        // 256 KB -> 540928
  ushort_t* W2r    = (ushort_t*)(ws + 540928);        // 1.125 MB -> 1720576
  ushort_t* y1Tp   = (ushort_t*)(ws + 1720576);       // 17.0 MB -> 19562752
  ushort_t* y2T    = (ushort_t*)(ws + 19562752);      // 16 MB -> ~36.3 MB total
  // xT scratch lives in d_out (67 MB fp32 >= 33.5 MB bf16); conv3 overwrites
  // every element of d_out afterwards, so this is safe.
  ushort_t* xT     = (ushort_t*)d_out;

  hipMemsetAsync(y1Tp, 0, (size_t)BB * PPX * HID * 2, stream);  // zero pads
  k_wcvt  <<<256, 256, 0, stream>>>(W1, W3, W1b, W3b);
  k_repack<<<2304, 256, 0, stream>>>(W2, W2r);
  k_xpose <<<dim3(64, 4, 16), 256, 0, stream>>>(x, xT);
  k_pool  <<<dim3(16, 16), 256, 0, stream>>>(x, pooled);
  k_router<<<16, 128, 0, stream>>>(pooled, Wr1, br1, Wr2, br2, eidx, gatew);
  k_conv1 <<<dim3(32, 16), 256, 0, stream>>>(xT, W1b, eidx, y1Tp);
  k_conv2 <<<dim3(32, 16), 256, 0, stream>>>(y1Tp, W2r, eidx, y2T);
  k_conv3 <<<dim3(32, 2, 16), 256, 0, stream>>>(y2T, W3b, x, eidx, gatew, out);
}

// Round 3
// 209.544 us; speedup vs baseline: 1.1154x; 1.1154x over previous
//
#include <hip/hip_runtime.h>

typedef unsigned short ushort_t;
typedef unsigned int uint32;
typedef __attribute__((ext_vector_type(8))) short s16x8;   // 8 bf16 in 4 VGPRs
typedef __attribute__((ext_vector_type(4))) float f32x4;   // MFMA accumulator

#define BB   16
#define CC   256
#define NPX  4096          // 64*64 pixels
#define EE   4
#define HID  128
#define RHH  128
#define PW   66            // padded image width
#define PPX  (66*66)       // padded pixels per image

__device__ __forceinline__ ushort_t f2bf(float f) {
  uint32 x = __float_as_uint(f);
  x += 0x7fffu + ((x >> 16) & 1u);           // round-to-nearest-even
  return (ushort_t)(x >> 16);
}
// async global->LDS, 16B per lane; lds ptr wave-uniform (HW adds lane*16)
__device__ __forceinline__ void g2l16(const void* g, void* l) {
  __builtin_amdgcn_global_load_lds((const __attribute__((address_space(1))) uint32*)g,
                                   (__attribute__((address_space(3))) uint32*)l, 16, 0, 0);
}

// ---------- x[b][c][px] fp32 -> xT[b][px][c] bf16 + fused global pooling ----------
__global__ __launch_bounds__(256)
void k_xpose(const float* __restrict__ x, ushort_t* __restrict__ xT,
             float* __restrict__ pooled) {
  int px0 = blockIdx.x * 64, c0 = blockIdx.y * 64, b = blockIdx.z;
  int t = threadIdx.x;
  __shared__ float T[64][65];
  const float* xg = x + (size_t)b * CC * NPX;
  int cr = t >> 4, p4 = (t & 15) * 4;
#pragma unroll
  for (int i = 0; i < 4; ++i) {
    float4 v = *(const float4*)(xg + (size_t)(c0 + cr + i * 16) * NPX + px0 + p4);
    T[cr + i * 16][p4 + 0] = v.x; T[cr + i * 16][p4 + 1] = v.y;
    T[cr + i * 16][p4 + 2] = v.z; T[cr + i * 16][p4 + 3] = v.w;
  }
  __syncthreads();
  // fused pooling: raw sums (router divides by NPX). c = t>>2, quarter = t&3.
  {
    int c = t >> 2, q = t & 3;
    float s = 0.f;
#pragma unroll
    for (int k = 0; k < 16; ++k) s += T[c][q * 16 + k];
    s += __shfl_down(s, 1, 64);
    s += __shfl_down(s, 2, 64);
    if (q == 0) atomicAdd(&pooled[b * CC + c0 + c], s);
  }
  int px = t >> 2, cg = (t & 3) * 16;
  uint32 o[8];
#pragma unroll
  for (int u = 0; u < 8; ++u) {
    uint32 lo = f2bf(T[cg + 2 * u][px]);
    uint32 hi = f2bf(T[cg + 2 * u + 1][px]);
    o[u] = lo | (hi << 16);
  }
  ushort_t* dst = xT + ((size_t)b * NPX + px0 + px) * CC + c0 + cg;
  *(uint4*)dst = make_uint4(o[0], o[1], o[2], o[3]);
  *(uint4*)(dst + 8) = make_uint4(o[4], o[5], o[6], o[7]);
}

// ---------- prep: W1/W3 fp32->bf16 copy + W2 [E][O][I][3][3] -> [E][tap][O][I] ----------
__global__ __launch_bounds__(256)
void k_prep(const float* __restrict__ W1f, const float* __restrict__ W3f,
            const float* __restrict__ W2f, ushort_t* __restrict__ W1b,
            ushort_t* __restrict__ W3b, ushort_t* __restrict__ W2r) {
  int bid = blockIdx.x;
  if (bid < 256) {            // W1/W3 convert, 4 elems/thread
    int i4 = (bid * 256 + threadIdx.x) * 4;
    const float* src; ushort_t* dst; int off;
    if (i4 < EE * HID * CC) { src = W1f; dst = W1b; off = i4; }
    else { src = W3f; dst = W3b; off = i4 - EE * HID * CC; }
    float4 v = *(const float4*)(src + off);
    ushort4 o;
    o.x = f2bf(v.x); o.y = f2bf(v.y); o.z = f2bf(v.z); o.w = f2bf(v.w);
    *(ushort4*)(dst + off) = o;
  } else {                    // W2 repack+convert, 1 elem/thread
    int i = (bid - 256) * 256 + threadIdx.x;   // i = ((e*9+tap)*128+g)*128+h
    int h = i & 127;
    int g = (i >> 7) & 127;
    int et = i >> 14;
    int tap = et % 9;
    int e = et / 9;
    W2r[i] = f2bf(W2f[((((size_t)e * 128 + g) * 128 + h) * 3 + tap / 3) * 3 + tap % 3]);
  }
}

// ---------- router: MLP + softmax + top-1 (fp32) ----------
__global__ __launch_bounds__(128)
void k_router(const float* __restrict__ pooled, const float* __restrict__ Wr1,
              const float* __restrict__ br1, const float* __restrict__ Wr2,
              const float* __restrict__ br2, int* __restrict__ eidx,
              float* __restrict__ gatew) {
  int b = blockIdx.x, t = threadIdx.x;
  __shared__ float hb[RHH];
  __shared__ float lg[EE];
  float s0 = 0.f;
  const float* pb = pooled + b * CC;   // raw sums; scale by 1/NPX below
  const float* wr = Wr1 + t * CC;
  for (int c = 0; c < CC; ++c) s0 += pb[c] * wr[c];
  float a = br1[t] + s0 * (1.0f / NPX);
  hb[t] = a > 0.f ? a : 0.f;
  __syncthreads();
  if (t < EE) {
    float s = br2[t];
    const float* w2 = Wr2 + t * RHH;
    for (int r = 0; r < RHH; ++r) s += hb[r] * w2[r];
    lg[t] = s;
  }
  __syncthreads();
  if (t == 0) {
    float m = lg[0]; int mi = 0;
    for (int e = 1; e < EE; ++e) if (lg[e] > m) { m = lg[e]; mi = e; }  // first-max = lax.top_k tie rule
    float den = 0.f;
    for (int e = 0; e < EE; ++e) den += expf(lg[e] - m);
    float v = 1.0f / den;                 // softmax value at argmax
    eidx[b] = mi;
    gatew[b] = v / (v + 1e-9f);           // top-1 renormalized weight
  }
}

// ---------- conv1: 1x1 C->HID, relu -> zero-padded pixel-major y1 ----------
__global__ __launch_bounds__(256)
void k_conv1(const ushort_t* __restrict__ xT, const ushort_t* __restrict__ W1b,
             const int* __restrict__ eidx, ushort_t* __restrict__ y1Tp) {
  int mt = blockIdx.x, b = blockIdx.y;
  int e = eidx[b];
  int t = threadIdx.x, wave = t >> 6, lane = t & 63;
  int wm = (wave & 1) * 64, wn = (wave >> 1) * 64;
  __shared__ ushort_t At[128 * 32];
  __shared__ ushort_t Bt[128 * 32];
  f32x4 acc[4][4] = {};
  const ushort_t* ab = xT + ((size_t)b * NPX + mt * 128) * CC;
  const ushort_t* w1 = W1b + (size_t)e * HID * CC;

  for (int ks = 0; ks < 8; ++ks) {
    int k0 = ks * 32;
    __syncthreads();
#pragma unroll
    for (int s = 0; s < 2; ++s) {
      int q = wave * 2 + s;
      int rowi = q * 16 + (lane >> 2);
      int kc = (lane & 3) * 8;
      g2l16(ab + (size_t)rowi * CC + k0 + kc, &At[q * 512]);
      g2l16(w1 + (size_t)rowi * CC + k0 + kc, &Bt[q * 512]);
    }
    __syncthreads();
    s16x8 af[4], bfr[4];
#pragma unroll
    for (int i = 0; i < 4; ++i)
      af[i] = *(const s16x8*)&At[(wm + i * 16 + (lane & 15)) * 32 + (lane >> 4) * 8];
#pragma unroll
    for (int j = 0; j < 4; ++j)
      bfr[j] = *(const s16x8*)&Bt[(wn + j * 16 + (lane & 15)) * 32 + (lane >> 4) * 8];
#pragma unroll
    for (int i = 0; i < 4; ++i)
#pragma unroll
      for (int j = 0; j < 4; ++j)
        acc[i][j] = __builtin_amdgcn_mfma_f32_16x16x32_bf16(af[i], bfr[j], acc[i][j], 0, 0, 0);
  }
  ushort_t* yb = y1Tp + (size_t)b * PPX * HID;
#pragma unroll
  for (int i = 0; i < 4; ++i) {
#pragma unroll
    for (int r = 0; r < 4; ++r) {
      int m = wm + i * 16 + (lane >> 4) * 4 + r;
      int prow = mt * 2 + (m >> 6) + 1;
      int pcol = (m & 63) + 1;
      ushort_t* row = yb + ((size_t)prow * PW + pcol) * HID + wn + (lane & 15);
#pragma unroll
      for (int j = 0; j < 4; ++j) {
        float v = acc[i][j][r];
        row[j * 16] = f2bf(v > 0.f ? v : 0.f);
      }
    }
  }
}

// ---------- conv2: 3x3 HID->HID as 9 shifted GEMM taps ----------
__global__ __launch_bounds__(256)
void k_conv2(const ushort_t* __restrict__ y1Tp, const ushort_t* __restrict__ W2r,
             const int* __restrict__ eidx, ushort_t* __restrict__ y2T) {
  int mt = blockIdx.x, b = blockIdx.y;
  int e = eidx[b];
  int t = threadIdx.x, wave = t >> 6, lane = t & 63;
  int wm = (wave & 1) * 64, wn = (wave >> 1) * 64;
  __shared__ ushort_t At[128 * 32];
  __shared__ ushort_t Bt[128 * 32];
  f32x4 acc[4][4] = {};
  const ushort_t* yb = y1Tp + (size_t)b * PPX * HID;
  const ushort_t* w2e = W2r + (size_t)e * 9 * HID * HID;

  for (int tap = 0; tap < 9; ++tap) {
    int dy = tap / 3 - 1, dx = tap % 3 - 1;
    const ushort_t* w2t = w2e + tap * HID * HID;
    for (int ks = 0; ks < 4; ++ks) {
      int k0 = ks * 32;
      __syncthreads();
#pragma unroll
      for (int s = 0; s < 2; ++s) {
        int q = wave * 2 + s;
        int rowi = q * 16 + (lane >> 2);
        int kc = (lane & 3) * 8;
        int prow = mt * 2 + (rowi >> 6) + 1 + dy;   // shifted padded pixel
        int pcol = (rowi & 63) + 1 + dx;
        g2l16(yb + ((size_t)prow * PW + pcol) * HID + k0 + kc, &At[q * 512]);
        g2l16(w2t + rowi * HID + k0 + kc, &Bt[q * 512]);
      }
      __syncthreads();
      s16x8 af[4], bfr[4];
#pragma unroll
      for (int i = 0; i < 4; ++i)
        af[i] = *(const s16x8*)&At[(wm + i * 16 + (lane & 15)) * 32 + (lane >> 4) * 8];
#pragma unroll
      for (int j = 0; j < 4; ++j)
        bfr[j] = *(const s16x8*)&Bt[(wn + j * 16 + (lane & 15)) * 32 + (lane >> 4) * 8];
#pragma unroll
      for (int i = 0; i < 4; ++i)
#pragma unroll
        for (int j = 0; j < 4; ++j)
          acc[i][j] = __builtin_amdgcn_mfma_f32_16x16x32_bf16(af[i], bfr[j], acc[i][j], 0, 0, 0);
    }
  }
  ushort_t* ob = y2T + ((size_t)b * NPX + (size_t)mt * 128) * HID;
#pragma unroll
  for (int i = 0; i < 4; ++i) {
#pragma unroll
    for (int r = 0; r < 4; ++r) {
      int m = wm + i * 16 + (lane >> 4) * 4 + r;
      ushort_t* row = ob + (size_t)m * HID + wn + (lane & 15);
#pragma unroll
      for (int j = 0; j < 4; ++j) {
        float v = acc[i][j][r];
        row[j * 16] = f2bf(v > 0.f ? v : 0.f);
      }
    }
  }
}

// ---------- conv3: 1x1 HID->C + gate + fp32 residual; LDS-coalesced epilogue ----------
__global__ __launch_bounds__(256)
void k_conv3(const ushort_t* __restrict__ y2T, const ushort_t* __restrict__ W3b,
             const float* __restrict__ x, const int* __restrict__ eidx,
             const float* __restrict__ gatew, float* __restrict__ out) {
  int mt = blockIdx.x, nt = blockIdx.y, b = blockIdx.z;
  int e = eidx[b];
  float gw = gatew[b];
  int t = threadIdx.x, wave = t >> 6, lane = t & 63;
  int wm = (wave & 1) * 64, wn = (wave >> 1) * 64;
  __shared__ ushort_t At[128 * 32];
  __shared__ ushort_t Bt[128 * 32];
  __shared__ float Tf[32 * 132];   // 32c x 128px staging, pitch 132 (<=2-way banks)
  f32x4 acc[4][4] = {};
  const ushort_t* yb = y2T + ((size_t)b * NPX + (size_t)mt * 128) * HID;
  const ushort_t* w3 = W3b + ((size_t)e * CC + nt * 128) * HID;

  for (int ks = 0; ks < 4; ++ks) {
    int k0 = ks * 32;
    __syncthreads();
#pragma unroll
    for (int s = 0; s < 2; ++s) {
      int q = wave * 2 + s;
      int rowi = q * 16 + (lane >> 2);
      int kc = (lane & 3) * 8;
      g2l16(yb + (size_t)rowi * HID + k0 + kc, &At[q * 512]);
      g2l16(w3 + (size_t)rowi * HID + k0 + kc, &Bt[q * 512]);
    }
    __syncthreads();
    s16x8 af[4], bfr[4];
#pragma unroll
    for (int i = 0; i < 4; ++i)
      af[i] = *(const s16x8*)&At[(wm + i * 16 + (lane & 15)) * 32 + (lane >> 4) * 8];
#pragma unroll
    for (int j = 0; j < 4; ++j)
      bfr[j] = *(const s16x8*)&Bt[(wn + j * 16 + (lane & 15)) * 32 + (lane >> 4) * 8];
#pragma unroll
    for (int i = 0; i < 4; ++i)
#pragma unroll
      for (int j = 0; j < 4; ++j)
        acc[i][j] = __builtin_amdgcn_mfma_f32_16x16x32_bf16(af[i], bfr[j], acc[i][j], 0, 0, 0);
  }
  // epilogue: 4 chunks of 32c x 128px through LDS -> fully coalesced fp32 I/O
  for (int jj = 0; jj < 4; ++jj) {
    __syncthreads();
    if ((wn >> 6) == (jj >> 1)) {     // the 2 waves holding this c-range
      int j0 = (jj & 1) * 2;
#pragma unroll
      for (int jd = 0; jd < 2; ++jd) {
        int cl = jd * 16 + (lane & 15);
#pragma unroll
        for (int i = 0; i < 4; ++i) {
          int pb = wm + i * 16 + (lane >> 4) * 4;
          *(f32x4*)&Tf[cl * 132 + pb] = acc[i][j0 + jd];   // 4 consecutive px
        }
      }
    }
    __syncthreads();
#pragma unroll
    for (int it = 0; it < 4; ++it) {
      int idx = it * 256 + t;          // 0..1023
      int crow = idx >> 5;             // 0..31
      int p4 = (idx & 31) * 4;
      int c = nt * 128 + jj * 32 + crow;
      int px = mt * 128 + p4;
      size_t base = ((size_t)b * CC + c) * NPX + px;
      f32x4 vv = *(const f32x4*)&Tf[crow * 132 + p4];
      f32x4 xa = *(const f32x4*)(x + base);
      vv = gw * vv + xa;
      __builtin_nontemporal_store(vv, (f32x4*)(out + base));
    }
  }
}

extern "C" void kernel_launch(void* const* d_in, const int* in_sizes, int n_in,
                              void* d_out, int out_size, void* d_ws, size_t ws_size,
                              hipStream_t stream) {
  const float* x   = (const float*)d_in[0];
  const float* Wr1 = (const float*)d_in[1];
  const float* br1 = (const float*)d_in[2];
  const float* Wr2 = (const float*)d_in[3];
  const float* br2 = (const float*)d_in[4];
  const float* W1  = (const float*)d_in[5];
  const float* W2  = (const float*)d_in[6];
  const float* W3  = (const float*)d_in[7];
  float* out = (float*)d_out;

  char* ws = (char*)d_ws;
  int*      eidx   = (int*)ws;                        // 64 B
  float*    gatew  = (float*)(ws + 64);               // 64 B
  float*    pooled = (float*)(ws + 256);              // 16 KB -> 16640
  ushort_t* W1b    = (ushort_t*)(ws + 16640);         // 256 KB -> 278784
  ushort_t* W3b    = (ushort_t*)(ws + 278784);        // 256 KB -> 540928
  ushort_t* W2r    = (ushort_t*)(ws + 540928);        // 1.125 MB -> 1720576
  ushort_t* y1Tp   = (ushort_t*)(ws + 1720576);       // 17.0 MB -> 19562752
  ushort_t* y2T    = (ushort_t*)(ws + 19562752);      // 16 MB -> ~36.3 MB total
  // xT scratch lives in d_out (67 MB fp32 >= 33.5 MB bf16); conv3 overwrites
  // every element of d_out afterwards, so this is safe.
  ushort_t* xT     = (ushort_t*)d_out;

  hipMemsetAsync(y1Tp, 0, (size_t)BB * PPX * HID * 2, stream);  // zero pads
  hipMemsetAsync(pooled, 0, (size_t)BB * CC * 4, stream);       // pool accumulators
  k_prep  <<<2560, 256, 0, stream>>>(W1, W3, W2, W1b, W3b, W2r);
  k_xpose <<<dim3(64, 4, 16), 256, 0, stream>>>(x, xT, pooled);
  k_router<<<16, 128, 0, stream>>>(pooled, Wr1, br1, Wr2, br2, eidx, gatew);
  k_conv1 <<<dim3(32, 16), 256, 0, stream>>>(xT, W1b, eidx, y1Tp);
  k_conv2 <<<dim3(32, 16), 256, 0, stream>>>(y1Tp, W2r, eidx, y2T);
  k_conv3 <<<dim3(32, 2, 16), 256, 0, stream>>>(y2T, W3b, x, eidx, gatew, out);
}

// Round 4
// 195.626 us; speedup vs baseline: 1.1947x; 1.0711x over previous
//
#include <hip/hip_runtime.h>

typedef unsigned short ushort_t;
typedef unsigned int uint32;
typedef __attribute__((ext_vector_type(8))) short s16x8;   // 8 bf16 in 4 VGPRs
typedef __attribute__((ext_vector_type(4))) float f32x4;   // MFMA accumulator

#define BB   16
#define CC   256
#define NPX  4096          // 64*64 pixels
#define EE   4
#define HID  128
#define RHH  128
#define PW   66            // padded image width
#define PPX  (66*66)       // padded pixels per image

__device__ __forceinline__ ushort_t f2bf(float f) {
  uint32 x = __float_as_uint(f);
  x += 0x7fffu + ((x >> 16) & 1u);           // round-to-nearest-even
  return (ushort_t)(x >> 16);
}
// async global->LDS, 16B per lane; lds ptr wave-uniform (HW adds lane*16)
__device__ __forceinline__ void g2l16(const void* g, void* l) {
  __builtin_amdgcn_global_load_lds((const __attribute__((address_space(1))) uint32*)g,
                                   (__attribute__((address_space(3))) uint32*)l, 16, 0, 0);
}

// ---------- x[b][c][px] fp32 -> xT[b][px][c] bf16 + fused global pooling ----------
__global__ __launch_bounds__(256)
void k_xpose(const float* __restrict__ x, ushort_t* __restrict__ xT,
             float* __restrict__ pooled) {
  int px0 = blockIdx.x * 64, c0 = blockIdx.y * 64, b = blockIdx.z;
  int t = threadIdx.x;
  __shared__ float T[64][65];
  const float* xg = x + (size_t)b * CC * NPX;
  int cr = t >> 4, p4 = (t & 15) * 4;
#pragma unroll
  for (int i = 0; i < 4; ++i) {
    float4 v = *(const float4*)(xg + (size_t)(c0 + cr + i * 16) * NPX + px0 + p4);
    T[cr + i * 16][p4 + 0] = v.x; T[cr + i * 16][p4 + 1] = v.y;
    T[cr + i * 16][p4 + 2] = v.z; T[cr + i * 16][p4 + 3] = v.w;
  }
  __syncthreads();
  // fused pooling: raw sums (router divides by NPX). c = t>>2, quarter = t&3.
  {
    int c = t >> 2, q = t & 3;
    float s = 0.f;
#pragma unroll
    for (int k = 0; k < 16; ++k) s += T[c][q * 16 + k];
    s += __shfl_down(s, 1, 64);
    s += __shfl_down(s, 2, 64);
    if (q == 0) atomicAdd(&pooled[b * CC + c0 + c], s);
  }
  int px = t >> 2, cg = (t & 3) * 16;
  uint32 o[8];
#pragma unroll
  for (int u = 0; u < 8; ++u) {
    uint32 lo = f2bf(T[cg + 2 * u][px]);
    uint32 hi = f2bf(T[cg + 2 * u + 1][px]);
    o[u] = lo | (hi << 16);
  }
  ushort_t* dst = xT + ((size_t)b * NPX + px0 + px) * CC + c0 + cg;
  *(uint4*)dst = make_uint4(o[0], o[1], o[2], o[3]);
  *(uint4*)(dst + 8) = make_uint4(o[4], o[5], o[6], o[7]);
}

// ---------- prep: W converts + W2 repack + y1 pad-ring zero + pooled zero ----------
__global__ __launch_bounds__(256)
void k_prep(const float* __restrict__ W1f, const float* __restrict__ W3f,
            const float* __restrict__ W2f, ushort_t* __restrict__ W1b,
            ushort_t* __restrict__ W3b, ushort_t* __restrict__ W2r,
            ushort_t* __restrict__ y1Tp, float* __restrict__ pooled) {
  int bid = blockIdx.x, t = threadIdx.x;
  if (bid < 256) {            // W1/W3 convert, 4 elems/thread
    int i4 = (bid * 256 + t) * 4;
    const float* src; ushort_t* dst; int off;
    if (i4 < EE * HID * CC) { src = W1f; dst = W1b; off = i4; }
    else { src = W3f; dst = W3b; off = i4 - EE * HID * CC; }
    float4 v = *(const float4*)(src + off);
    ushort4 o;
    o.x = f2bf(v.x); o.y = f2bf(v.y); o.z = f2bf(v.z); o.w = f2bf(v.w);
    *(ushort4*)(dst + off) = o;
  } else if (bid < 2560) {    // W2 repack+convert, 1 elem/thread
    int i = (bid - 256) * 256 + t;   // i = ((e*9+tap)*128+g)*128+h
    int h = i & 127;
    int g = (i >> 7) & 127;
    int et = i >> 14;
    int tap = et % 9;
    int e = et / 9;
    W2r[i] = f2bf(W2f[((((size_t)e * 128 + g) * 128 + h) * 3 + tap / 3) * 3 + tap % 3]);
  } else if (bid < 3080) {    // y1 pad ring: 260 pad px/batch, 128ch, zero
    int p = (bid - 2560) * 8 + (t >> 5);      // pad-pixel index, 32 lanes each
    int b = p / 260, i = p % 260;
    int row, col;
    if (i < 66)       { row = 0;       col = i; }
    else if (i < 132) { row = 65;      col = i - 66; }
    else if (i < 196) { row = i - 131; col = 0; }
    else              { row = i - 195; col = 65; }
    uint2* dst = (uint2*)(y1Tp + (((size_t)b * PPX + row * PW + col) * HID) + (t & 31) * 4);
    *dst = make_uint2(0u, 0u);
  } else {                    // pooled accumulators zero
#pragma unroll
    for (int i = 0; i < 4; ++i)
      *(float4*)&pooled[t * 16 + i * 4] = make_float4(0.f, 0.f, 0.f, 0.f);
  }
}

// ---------- router: MLP + softmax + top-1 (fp32) ----------
__global__ __launch_bounds__(128)
void k_router(const float* __restrict__ pooled, const float* __restrict__ Wr1,
              const float* __restrict__ br1, const float* __restrict__ Wr2,
              const float* __restrict__ br2, int* __restrict__ eidx,
              float* __restrict__ gatew) {
  int b = blockIdx.x, t = threadIdx.x;
  __shared__ float hb[RHH];
  __shared__ float lg[EE];
  float s0 = 0.f;
  const float* pb = pooled + b * CC;   // raw sums; scale by 1/NPX below
  const float* wr = Wr1 + t * CC;
  for (int c = 0; c < CC; ++c) s0 += pb[c] * wr[c];
  float a = br1[t] + s0 * (1.0f / NPX);
  hb[t] = a > 0.f ? a : 0.f;
  __syncthreads();
  if (t < EE) {
    float s = br2[t];
    const float* w2 = Wr2 + t * RHH;
    for (int r = 0; r < RHH; ++r) s += hb[r] * w2[r];
    lg[t] = s;
  }
  __syncthreads();
  if (t == 0) {
    float m = lg[0]; int mi = 0;
    for (int e = 1; e < EE; ++e) if (lg[e] > m) { m = lg[e]; mi = e; }  // first-max = lax.top_k tie rule
    float den = 0.f;
    for (int e = 0; e < EE; ++e) den += expf(lg[e] - m);
    float v = 1.0f / den;                 // softmax value at argmax
    eidx[b] = mi;
    gatew[b] = v / (v + 1e-9f);           // top-1 renormalized weight
  }
}

// BK=64 tile: rows are 128B; 16B chunks XOR-swizzled (chunk^row&7) so that
// ds_read_b128 fragment reads spread across banks. Swizzle is applied on the
// GLOBAL address side of global_load_lds (its LDS side is fixed lane*16).
#define STAGE64(dstA, srcA_expr, dstB, srcB_expr)                         \
  {                                                                       \
    _Pragma("unroll")                                                     \
    for (int s_ = 0; s_ < 4; ++s_) {                                      \
      int ch_ = wave * 4 + s_;                                            \
      int r = ch_ * 8 + (lane >> 3);                                      \
      int kc = ((lane & 7) ^ (lane >> 3)) * 8;                            \
      g2l16(srcA_expr, &dstA[ch_ * 512]);                                 \
      g2l16(srcB_expr, &dstB[ch_ * 512]);                                 \
    }                                                                     \
  }

#define MFMA64(At_, Bt_)                                                  \
  _Pragma("unroll")                                                       \
  for (int kh = 0; kh < 2; ++kh) {                                        \
    s16x8 af[4], bfr[4];                                                  \
    int cidx = ((kh * 4 + (lane >> 4)) ^ (lane & 7)) * 8;                 \
    _Pragma("unroll")                                                     \
    for (int i = 0; i < 4; ++i)                                           \
      af[i] = *(const s16x8*)&At_[(wm + i * 16 + (lane & 15)) * 64 + cidx]; \
    _Pragma("unroll")                                                     \
    for (int j = 0; j < 4; ++j)                                           \
      bfr[j] = *(const s16x8*)&Bt_[(wn + j * 16 + (lane & 15)) * 64 + cidx]; \
    _Pragma("unroll")                                                     \
    for (int i = 0; i < 4; ++i)                                           \
      _Pragma("unroll")                                                   \
      for (int j = 0; j < 4; ++j)                                         \
        acc[i][j] = __builtin_amdgcn_mfma_f32_16x16x32_bf16(af[i], bfr[j], acc[i][j], 0, 0, 0); \
  }

// ---------- conv1: 1x1 C->HID, relu -> zero-padded pixel-major y1 ----------
__global__ __launch_bounds__(256)
void k_conv1(const ushort_t* __restrict__ xT, const ushort_t* __restrict__ W1b,
             const int* __restrict__ eidx, ushort_t* __restrict__ y1Tp) {
  int mt = blockIdx.x, b = blockIdx.y;
  int e = eidx[b];
  int t = threadIdx.x, wave = t >> 6, lane = t & 63;
  int wm = (wave & 1) * 64, wn = (wave >> 1) * 64;
  __shared__ ushort_t At[128 * 64];
  __shared__ ushort_t Bt[128 * 64];
  f32x4 acc[4][4] = {};
  const ushort_t* ab = xT + ((size_t)b * NPX + mt * 128) * CC;
  const ushort_t* w1 = W1b + (size_t)e * HID * CC;

  for (int ks = 0; ks < 4; ++ks) {
    int k0 = ks * 64;
    __syncthreads();
    STAGE64(At, ab + (size_t)r * CC + k0 + kc,
            Bt, w1 + (size_t)r * CC + k0 + kc);
    __syncthreads();
    MFMA64(At, Bt);
  }
  ushort_t* yb = y1Tp + (size_t)b * PPX * HID;
#pragma unroll
  for (int i = 0; i < 4; ++i) {
#pragma unroll
    for (int r = 0; r < 4; ++r) {
      int m = wm + i * 16 + (lane >> 4) * 4 + r;
      int prow = mt * 2 + (m >> 6) + 1;
      int pcol = (m & 63) + 1;
      ushort_t* row = yb + ((size_t)prow * PW + pcol) * HID + wn + (lane & 15);
#pragma unroll
      for (int j = 0; j < 4; ++j) {
        float v = acc[i][j][r];
        row[j * 16] = f2bf(v > 0.f ? v : 0.f);
      }
    }
  }
}

// ---------- conv2: 3x3 HID->HID as 9 shifted GEMM taps ----------
__global__ __launch_bounds__(256)
void k_conv2(const ushort_t* __restrict__ y1Tp, const ushort_t* __restrict__ W2r,
             const int* __restrict__ eidx, ushort_t* __restrict__ y2T) {
  int mt = blockIdx.x, b = blockIdx.y;
  int e = eidx[b];
  int t = threadIdx.x, wave = t >> 6, lane = t & 63;
  int wm = (wave & 1) * 64, wn = (wave >> 1) * 64;
  __shared__ ushort_t At[128 * 64];
  __shared__ ushort_t Bt[128 * 64];
  f32x4 acc[4][4] = {};
  const ushort_t* yb = y1Tp + (size_t)b * PPX * HID;
  const ushort_t* w2e = W2r + (size_t)e * 9 * HID * HID;

  for (int tap = 0; tap < 9; ++tap) {
    int dy = tap / 3 - 1, dx = tap % 3 - 1;
    const ushort_t* w2t = w2e + tap * HID * HID;
#pragma unroll
    for (int ks = 0; ks < 2; ++ks) {
      int k0 = ks * 64;
      __syncthreads();
      STAGE64(At, yb + ((size_t)(mt * 2 + (r >> 6) + 1 + dy) * PW + (r & 63) + 1 + dx) * HID + k0 + kc,
              Bt, w2t + (size_t)r * HID + k0 + kc);
      __syncthreads();
      MFMA64(At, Bt);
    }
  }
  ushort_t* ob = y2T + ((size_t)b * NPX + (size_t)mt * 128) * HID;
#pragma unroll
  for (int i = 0; i < 4; ++i) {
#pragma unroll
    for (int r = 0; r < 4; ++r) {
      int m = wm + i * 16 + (lane >> 4) * 4 + r;
      ushort_t* row = ob + (size_t)m * HID + wn + (lane & 15);
#pragma unroll
      for (int j = 0; j < 4; ++j) {
        float v = acc[i][j][r];
        row[j * 16] = f2bf(v > 0.f ? v : 0.f);
      }
    }
  }
}

// ---------- conv3: 1x1 HID->C + gate + fp32 residual; LDS-coalesced epilogue ----------
__global__ __launch_bounds__(256)
void k_conv3(const ushort_t* __restrict__ y2T, const ushort_t* __restrict__ W3b,
             const float* __restrict__ x, const int* __restrict__ eidx,
             const float* __restrict__ gatew, float* __restrict__ out) {
  int mt = blockIdx.x, nt = blockIdx.y, b = blockIdx.z;
  int e = eidx[b];
  float gw = gatew[b];
  int t = threadIdx.x, wave = t >> 6, lane = t & 63;
  int wm = (wave & 1) * 64, wn = (wave >> 1) * 64;
  __shared__ ushort_t At[128 * 64];
  __shared__ ushort_t Bt[128 * 64];
  __shared__ float Tf[32 * 132];   // 32c x 128px staging, pitch 132 (<=2-way banks)
  f32x4 acc[4][4] = {};
  const ushort_t* yb = y2T + ((size_t)b * NPX + (size_t)mt * 128) * HID;
  const ushort_t* w3 = W3b + ((size_t)e * CC + nt * 128) * HID;

#pragma unroll
  for (int ks = 0; ks < 2; ++ks) {
    int k0 = ks * 64;
    __syncthreads();
    STAGE64(At, yb + (size_t)r * HID + k0 + kc,
            Bt, w3 + (size_t)r * HID + k0 + kc);
    __syncthreads();
    MFMA64(At, Bt);
  }
  // epilogue: 4 chunks of 32c x 128px through LDS -> fully coalesced fp32 I/O
  for (int jj = 0; jj < 4; ++jj) {
    __syncthreads();
    if ((wn >> 6) == (jj >> 1)) {     // the 2 waves holding this c-range
      int j0 = (jj & 1) * 2;
#pragma unroll
      for (int jd = 0; jd < 2; ++jd) {
        int cl = jd * 16 + (lane & 15);
#pragma unroll
        for (int i = 0; i < 4; ++i) {
          int pb = wm + i * 16 + (lane >> 4) * 4;
          *(f32x4*)&Tf[cl * 132 + pb] = acc[i][j0 + jd];   // 4 consecutive px
        }
      }
    }
    __syncthreads();
#pragma unroll
    for (int it = 0; it < 4; ++it) {
      int idx = it * 256 + t;          // 0..1023
      int crow = idx >> 5;             // 0..31
      int p4 = (idx & 31) * 4;
      int c = nt * 128 + jj * 32 + crow;
      int px = mt * 128 + p4;
      size_t base = ((size_t)b * CC + c) * NPX + px;
      f32x4 vv = *(const f32x4*)&Tf[crow * 132 + p4];
      f32x4 xa = *(const f32x4*)(x + base);
      vv = gw * vv + xa;
      __builtin_nontemporal_store(vv, (f32x4*)(out + base));
    }
  }
}

extern "C" void kernel_launch(void* const* d_in, const int* in_sizes, int n_in,
                              void* d_out, int out_size, void* d_ws, size_t ws_size,
                              hipStream_t stream) {
  const float* x   = (const float*)d_in[0];
  const float* Wr1 = (const float*)d_in[1];
  const float* br1 = (const float*)d_in[2];
  const float* Wr2 = (const float*)d_in[3];
  const float* br2 = (const float*)d_in[4];
  const float* W1  = (const float*)d_in[5];
  const float* W2  = (const float*)d_in[6];
  const float* W3  = (const float*)d_in[7];
  float* out = (float*)d_out;

  char* ws = (char*)d_ws;
  int*      eidx   = (int*)ws;                        // 64 B
  float*    gatew  = (float*)(ws + 64);               // 64 B
  float*    pooled = (float*)(ws + 256);              // 16 KB -> 16640
  ushort_t* W1b    = (ushort_t*)(ws + 16640);         // 256 KB -> 278784
  ushort_t* W3b    = (ushort_t*)(ws + 278784);        // 256 KB -> 540928
  ushort_t* W2r    = (ushort_t*)(ws + 540928);        // 1.125 MB -> 1720576
  ushort_t* y1Tp   = (ushort_t*)(ws + 1720576);       // 17.0 MB -> 19562752
  ushort_t* y2T    = (ushort_t*)(ws + 19562752);      // 16 MB -> ~36.3 MB total
  // xT scratch lives in d_out (67 MB fp32 >= 33.5 MB bf16); conv3 overwrites
  // every element of d_out afterwards, so this is safe.
  ushort_t* xT     = (ushort_t*)d_out;

  k_prep  <<<3081, 256, 0, stream>>>(W1, W3, W2, W1b, W3b, W2r, y1Tp, pooled);
  k_xpose <<<dim3(64, 4, 16), 256, 0, stream>>>(x, xT, pooled);
  k_router<<<16, 128, 0, stream>>>(pooled, Wr1, br1, Wr2, br2, eidx, gatew);
  k_conv1 <<<dim3(32, 16), 256, 0, stream>>>(xT, W1b, eidx, y1Tp);
  k_conv2 <<<dim3(32, 16), 256, 0, stream>>>(y1Tp, W2r, eidx, y2T);
  k_conv3 <<<dim3(32, 2, 16), 256, 0, stream>>>(y2T, W3b, x, eidx, gatew, out);
}

// Round 5
// 189.147 us; speedup vs baseline: 1.2357x; 1.0343x over previous
//
#include <hip/hip_runtime.h>

typedef unsigned short ushort_t;
typedef unsigned int uint32;
typedef __attribute__((ext_vector_type(8))) short s16x8;   // 8 bf16 in 4 VGPRs
typedef __attribute__((ext_vector_type(4))) float f32x4;   // MFMA accumulator

#define BB   16
#define CC   256
#define NPX  4096          // 64*64 pixels
#define EE   4
#define HID  128
#define RHH  128
#define PW   66            // padded image width
#define PPX  (66*66)       // padded pixels per image

__device__ __forceinline__ ushort_t f2bf(float f) {
  uint32 x = __float_as_uint(f);
  x += 0x7fffu + ((x >> 16) & 1u);           // round-to-nearest-even
  return (ushort_t)(x >> 16);
}
// async global->LDS, 16B per lane; lds ptr wave-uniform (HW adds lane*16)
__device__ __forceinline__ void g2l16(const void* g, void* l) {
  __builtin_amdgcn_global_load_lds((const __attribute__((address_space(1))) uint32*)g,
                                   (__attribute__((address_space(3))) uint32*)l, 16, 0, 0);
}

// ---------- fused: x transpose+cvt + pooling partials + weight prep ----------
__global__ __launch_bounds__(256)
void k_xprep(const float* __restrict__ x, ushort_t* __restrict__ xT,
             float* __restrict__ part,
             const float* __restrict__ W1f, const float* __restrict__ W3f,
             const float* __restrict__ W2f, ushort_t* __restrict__ W1b,
             ushort_t* __restrict__ W3b, ushort_t* __restrict__ W2r,
             ushort_t* __restrict__ y1Tp) {
  int bid = blockIdx.x, t = threadIdx.x;
  if (bid < 4096) {           // xpose: block = (pxblk, cblk, b)
    int pxblk = bid & 63, c0 = ((bid >> 6) & 3) * 64, b = bid >> 8;
    int px0 = pxblk * 64;
    __shared__ float T[64][65];
    const float* xg = x + (size_t)b * CC * NPX;
    int cr = t >> 4, p4 = (t & 15) * 4;
#pragma unroll
    for (int i = 0; i < 4; ++i) {
      float4 v = *(const float4*)(xg + (size_t)(c0 + cr + i * 16) * NPX + px0 + p4);
      T[cr + i * 16][p4 + 0] = v.x; T[cr + i * 16][p4 + 1] = v.y;
      T[cr + i * 16][p4 + 2] = v.z; T[cr + i * 16][p4 + 3] = v.w;
    }
    __syncthreads();
    {   // pooling partial: race-free, no atomics (router reduces the 64 partials)
      int c = t >> 2, q = t & 3;
      float s = 0.f;
#pragma unroll
      for (int k = 0; k < 16; ++k) s += T[c][q * 16 + k];
      s += __shfl_down(s, 1, 64);
      s += __shfl_down(s, 2, 64);
      if (q == 0) part[((size_t)b * CC + c0 + c) * 64 + pxblk] = s;
    }
    int px = t >> 2, cg = (t & 3) * 16;
    uint32 o[8];
#pragma unroll
    for (int u = 0; u < 8; ++u) {
      uint32 lo = f2bf(T[cg + 2 * u][px]);
      uint32 hi = f2bf(T[cg + 2 * u + 1][px]);
      o[u] = lo | (hi << 16);
    }
    ushort_t* dst = xT + ((size_t)b * NPX + px0 + px) * CC + c0 + cg;
    *(uint4*)dst = make_uint4(o[0], o[1], o[2], o[3]);
    *(uint4*)(dst + 8) = make_uint4(o[4], o[5], o[6], o[7]);
  } else if (bid < 4352) {    // W1/W3 convert, 4 elems/thread
    int i4 = ((bid - 4096) * 256 + t) * 4;
    const float* src; ushort_t* dst; int off;
    if (i4 < EE * HID * CC) { src = W1f; dst = W1b; off = i4; }
    else { src = W3f; dst = W3b; off = i4 - EE * HID * CC; }
    float4 v = *(const float4*)(src + off);
    ushort4 o;
    o.x = f2bf(v.x); o.y = f2bf(v.y); o.z = f2bf(v.z); o.w = f2bf(v.w);
    *(ushort4*)(dst + off) = o;
  } else if (bid < 6656) {    // W2 repack+convert, 1 elem/thread
    int i = (bid - 4352) * 256 + t;   // i = ((e*9+tap)*128+g)*128+h
    int h = i & 127;
    int g = (i >> 7) & 127;
    int et = i >> 14;
    int tap = et % 9;
    int e = et / 9;
    W2r[i] = f2bf(W2f[((((size_t)e * 128 + g) * 128 + h) * 3 + tap / 3) * 3 + tap % 3]);
  } else {                    // y1 pad ring: 260 pad px/batch, 128ch, zero
    int p = (bid - 6656) * 8 + (t >> 5);      // pad-pixel index, 32 lanes each
    int b = p / 260, i = p % 260;
    int row, col;
    if (i < 66)       { row = 0;       col = i; }
    else if (i < 132) { row = 65;      col = i - 66; }
    else if (i < 196) { row = i - 131; col = 0; }
    else              { row = i - 195; col = 65; }
    uint2* dst = (uint2*)(y1Tp + (((size_t)b * PPX + row * PW + col) * HID) + (t & 31) * 4);
    *dst = make_uint2(0u, 0u);
  }
}

// ---------- router: partial-reduce + MLP + softmax + top-1 (fp32) ----------
__global__ __launch_bounds__(128)
void k_router(const float* __restrict__ part, const float* __restrict__ Wr1,
              const float* __restrict__ br1, const float* __restrict__ Wr2,
              const float* __restrict__ br2, int* __restrict__ eidx,
              float* __restrict__ gatew) {
  int b = blockIdx.x, t = threadIdx.x;
  __shared__ float spool[CC];
  __shared__ float hb[RHH];
  __shared__ float lg[EE];
  for (int cc = t; cc < CC; cc += 128) {
    const float* pp = part + ((size_t)b * CC + cc) * 64;
    float s = 0.f;
#pragma unroll
    for (int k = 0; k < 64; ++k) s += pp[k];
    spool[cc] = s;                    // raw sum over all px
  }
  __syncthreads();
  float s0 = 0.f;
  const float* wr = Wr1 + t * CC;
  for (int c = 0; c < CC; ++c) s0 += spool[c] * wr[c];
  float a = br1[t] + s0 * (1.0f / NPX);
  hb[t] = a > 0.f ? a : 0.f;
  __syncthreads();
  if (t < EE) {
    float s = br2[t];
    const float* w2 = Wr2 + t * RHH;
    for (int r = 0; r < RHH; ++r) s += hb[r] * w2[r];
    lg[t] = s;
  }
  __syncthreads();
  if (t == 0) {
    float m = lg[0]; int mi = 0;
    for (int e = 1; e < EE; ++e) if (lg[e] > m) { m = lg[e]; mi = e; }  // first-max = lax.top_k tie rule
    float den = 0.f;
    for (int e = 0; e < EE; ++e) den += expf(lg[e] - m);
    float v = 1.0f / den;                 // softmax value at argmax
    eidx[b] = mi;
    gatew[b] = v / (v + 1e-9f);           // top-1 renormalized weight
  }
}

// BK=64 tile: rows are 128B; 16B chunks XOR-swizzled (chunk^row&7) so that
// ds_read_b128 fragment reads spread across banks. Swizzle applied on the
// GLOBAL address side of global_load_lds (its LDS side is fixed lane*16).
#define STAGE64(dstA, srcA_expr, dstB, srcB_expr)                         \
  {                                                                       \
    _Pragma("unroll")                                                     \
    for (int s_ = 0; s_ < 4; ++s_) {                                      \
      int ch_ = wave * 4 + s_;                                            \
      int r = ch_ * 8 + (lane >> 3);                                      \
      int kc = ((lane & 7) ^ (lane >> 3)) * 8;                            \
      g2l16(srcA_expr, &dstA[ch_ * 512]);                                 \
      g2l16(srcB_expr, &dstB[ch_ * 512]);                                 \
    }                                                                     \
  }

#define STAGE64B(dstB, srcB_expr)                                         \
  {                                                                       \
    _Pragma("unroll")                                                     \
    for (int s_ = 0; s_ < 4; ++s_) {                                      \
      int ch_ = wave * 4 + s_;                                            \
      int r = ch_ * 8 + (lane >> 3);                                      \
      int kc = ((lane & 7) ^ (lane >> 3)) * 8;                            \
      g2l16(srcB_expr, &dstB[ch_ * 512]);                                 \
    }                                                                     \
  }

#define MFMA64(At_, Bt_, ACC_)                                            \
  _Pragma("unroll")                                                       \
  for (int kh = 0; kh < 2; ++kh) {                                        \
    s16x8 af[4], bfr[4];                                                  \
    int cidx = ((kh * 4 + (lane >> 4)) ^ (lane & 7)) * 8;                 \
    _Pragma("unroll")                                                     \
    for (int i = 0; i < 4; ++i)                                           \
      af[i] = *(const s16x8*)&At_[(wm + i * 16 + (lane & 15)) * 64 + cidx]; \
    _Pragma("unroll")                                                     \
    for (int j = 0; j < 4; ++j)                                           \
      bfr[j] = *(const s16x8*)&Bt_[(wn + j * 16 + (lane & 15)) * 64 + cidx]; \
    _Pragma("unroll")                                                     \
    for (int i = 0; i < 4; ++i)                                           \
      _Pragma("unroll")                                                   \
      for (int j = 0; j < 4; ++j)                                         \
        ACC_[i][j] = __builtin_amdgcn_mfma_f32_16x16x32_bf16(af[i], bfr[j], ACC_[i][j], 0, 0, 0); \
  }

// ---------- conv1: 1x1 C->HID, relu -> zero-padded pixel-major y1 ----------
__global__ __launch_bounds__(256)
void k_conv1(const ushort_t* __restrict__ xT, const ushort_t* __restrict__ W1b,
             const int* __restrict__ eidx, ushort_t* __restrict__ y1Tp) {
  int mt = blockIdx.x, b = blockIdx.y;
  int e = eidx[b];
  int t = threadIdx.x, wave = t >> 6, lane = t & 63;
  int wm = (wave & 1) * 64, wn = (wave >> 1) * 64;
  __shared__ ushort_t At[128 * 64];
  __shared__ ushort_t Bt[128 * 64];
  f32x4 acc[4][4] = {};
  const ushort_t* ab = xT + ((size_t)b * NPX + mt * 128) * CC;
  const ushort_t* w1 = W1b + (size_t)e * HID * CC;

  for (int ks = 0; ks < 4; ++ks) {
    int k0 = ks * 64;
    __syncthreads();
    STAGE64(At, ab + (size_t)r * CC + k0 + kc,
            Bt, w1 + (size_t)r * CC + k0 + kc);
    __syncthreads();
    MFMA64(At, Bt, acc);
  }
  ushort_t* yb = y1Tp + (size_t)b * PPX * HID;
#pragma unroll
  for (int i = 0; i < 4; ++i) {
#pragma unroll
    for (int r = 0; r < 4; ++r) {
      int m = wm + i * 16 + (lane >> 4) * 4 + r;
      int prow = mt * 2 + (m >> 6) + 1;
      int pcol = (m & 63) + 1;
      ushort_t* row = yb + ((size_t)prow * PW + pcol) * HID + wn + (lane & 15);
#pragma unroll
      for (int j = 0; j < 4; ++j) {
        float v = acc[i][j][r];
        row[j * 16] = f2bf(v > 0.f ? v : 0.f);
      }
    }
  }
}

// ---------- fused conv2 (3x3 HID->HID) + conv3 (1x1 HID->C) + gate + residual ----------
// Phase 1: conv2 into acc (y2 tile 128px x 128h stays on-chip)
// Phase 2: relu+cvt acc -> swizzled LDS y2 tile (same layout MFMA64 reads)
// Phase 3: conv3, N=256 in two halves, K=128 from LDS y2
// Phase 4: LDS-coalesced fp32 epilogue (gw*acc3 + x -> out)
__global__ __launch_bounds__(256, 2)
void k_conv23(const ushort_t* __restrict__ y1Tp, const ushort_t* __restrict__ W2r,
              const ushort_t* __restrict__ W3b, const float* __restrict__ x,
              const int* __restrict__ eidx, const float* __restrict__ gatew,
              float* __restrict__ out) {
  int mt = blockIdx.x, b = blockIdx.y;
  int e = eidx[b];
  float gw = gatew[b];
  int t = threadIdx.x, wave = t >> 6, lane = t & 63;
  int wm = (wave & 1) * 64, wn = (wave >> 1) * 64;
  __shared__ ushort_t bufA[128 * 64];     // 16K: conv2 A-staging; conv3 W3 (ks=0)
  __shared__ ushort_t bufB[128 * 64];     // 16K: conv2 B-staging; conv3 W3 (ks=1)
  __shared__ ushort_t y2s[2][128 * 64];   // 32K: y2 tile (k-halves); epilogue Tf alias
  const ushort_t* yb = y1Tp + (size_t)b * PPX * HID;
  const ushort_t* w2e = W2r + (size_t)e * 9 * HID * HID;

  // ---- phase 1: conv2 ----
  f32x4 acc[4][4] = {};
  for (int tap = 0; tap < 9; ++tap) {
    int dy = tap / 3 - 1, dx = tap % 3 - 1;
    const ushort_t* w2t = w2e + tap * HID * HID;
#pragma unroll
    for (int ks = 0; ks < 2; ++ks) {
      int k0 = ks * 64;
      __syncthreads();
      STAGE64(bufA, yb + ((size_t)(mt * 2 + (r >> 6) + 1 + dy) * PW + (r & 63) + 1 + dx) * HID + k0 + kc,
              bufB, w2t + (size_t)r * HID + k0 + kc);
      __syncthreads();
      MFMA64(bufA, bufB, acc);
    }
  }
  // ---- phase 2: relu+cvt -> swizzled y2 LDS tile (each wave writes its own region) ----
#pragma unroll
  for (int i = 0; i < 4; ++i)
#pragma unroll
    for (int j = 0; j < 4; ++j)
#pragma unroll
      for (int r = 0; r < 4; ++r) {
        int m = wm + i * 16 + (lane >> 4) * 4 + r;
        int n = wn + j * 16 + (lane & 15);
        float v = acc[i][j][r];
        ushort_t bv = f2bf(v > 0.f ? v : 0.f);
        int nn = n & 63;
        ushort_t* buf = (n < 64) ? y2s[0] : y2s[1];   // wave-uniform select
        buf[m * 64 + ((nn >> 3) ^ (m & 7)) * 8 + (nn & 7)] = bv;
      }
  __syncthreads();
  // ---- phase 3: conv3, both 128-c halves, K=128 from y2s ----
  f32x4 acc3[2][4][4] = {};
  const ushort_t* w3 = W3b + (size_t)e * CC * HID;
#pragma unroll
  for (int h = 0; h < 2; ++h) {
#pragma unroll
    for (int ks = 0; ks < 2; ++ks) {
      ushort_t* bt = (ks == 0) ? bufA : bufB;
      STAGE64B(bt, w3 + (size_t)(h * 128 + r) * HID + ks * 64 + kc);
      __syncthreads();
      MFMA64(y2s[ks], bt, acc3[h]);
      // next STAGE64B overwrites only after all waves passed the barrier above,
      // and each wave's LDS reads complete before its own MFMAs -> WAR safe
    }
  }
  // ---- phase 4: coalesced epilogue, Tf aliases y2s (dead now) ----
  float* Tf = (float*)y2s;   // 32c x 128px, pitch 132 (16.9 KB < 32 KB)
  for (int h = 0; h < 2; ++h) {
    for (int jj = 0; jj < 4; ++jj) {
      __syncthreads();
      if ((wn >> 6) == (jj >> 1)) {     // the 2 waves holding this c-range
        int j0 = (jj & 1) * 2;
#pragma unroll
        for (int jd = 0; jd < 2; ++jd) {
          int cl = jd * 16 + (lane & 15);
#pragma unroll
          for (int i = 0; i < 4; ++i) {
            int pb = wm + i * 16 + (lane >> 4) * 4;
            *(f32x4*)&Tf[cl * 132 + pb] = acc3[h][i][j0 + jd];
          }
        }
      }
      __syncthreads();
#pragma unroll
      for (int it = 0; it < 4; ++it) {
        int idx = it * 256 + t;          // 0..1023
        int crow = idx >> 5;             // 0..31
        int p4 = (idx & 31) * 4;
        int c = h * 128 + jj * 32 + crow;
        int px = mt * 128 + p4;
        size_t base = ((size_t)b * CC + c) * NPX + px;
        f32x4 vv = *(const f32x4*)&Tf[crow * 132 + p4];
        f32x4 xa = *(const f32x4*)(x + base);
        vv = gw * vv + xa;
        __builtin_nontemporal_store(vv, (f32x4*)(out + base));
      }
    }
  }
}

extern "C" void kernel_launch(void* const* d_in, const int* in_sizes, int n_in,
                              void* d_out, int out_size, void* d_ws, size_t ws_size,
                              hipStream_t stream) {
  const float* x   = (const float*)d_in[0];
  const float* Wr1 = (const float*)d_in[1];
  const float* br1 = (const float*)d_in[2];
  const float* Wr2 = (const float*)d_in[3];
  const float* br2 = (const float*)d_in[4];
  const float* W1  = (const float*)d_in[5];
  const float* W2  = (const float*)d_in[6];
  const float* W3  = (const float*)d_in[7];
  float* out = (float*)d_out;

  char* ws = (char*)d_ws;
  int*      eidx  = (int*)ws;                         // 64 B
  float*    gatew = (float*)(ws + 64);                // 64 B -> 256
  float*    part  = (float*)(ws + 256);               // 1 MB pooling partials -> 1048832
  ushort_t* W1b   = (ushort_t*)(ws + 1048832);        // 256 KB -> 1310976
  ushort_t* W3b   = (ushort_t*)(ws + 1310976);        // 256 KB -> 1573120
  ushort_t* W2r   = (ushort_t*)(ws + 1573120);        // 1.125 MB -> 2752768
  ushort_t* y1Tp  = (ushort_t*)(ws + 2752768);        // 17.0 MB -> ~19.8 MB total
  // xT scratch lives in d_out (67 MB fp32 >= 33.5 MB bf16); conv23 overwrites
  // every element of d_out afterwards, so this is safe.
  ushort_t* xT    = (ushort_t*)d_out;

  k_xprep <<<7176, 256, 0, stream>>>(x, xT, part, W1, W3, W2, W1b, W3b, W2r, y1Tp);
  k_router<<<16, 128, 0, stream>>>(part, Wr1, br1, Wr2, br2, eidx, gatew);
  k_conv1 <<<dim3(32, 16), 256, 0, stream>>>(xT, W1b, eidx, y1Tp);
  k_conv23<<<dim3(32, 16), 256, 0, stream>>>(y1Tp, W2r, W3b, x, eidx, gatew, out);
}